// Round 15
// baseline (755.126 us; speedup 1.0000x reference)
//
#include <hip/hip_runtime.h>

#define HD 64      // hidden/feature dim (D == H == 64)
#define PSUB 16    // partial slots per graph (pool accumulation spread)
#define NBLK 256   // histogram blocks (edge slices)
#define LOG_NBLK 8
#define NBKT 512   // dst buckets (bucket = dst >> 7, 128 nodes each; N <= 65536)
#define GRID_BUILD 1024   // 4 blocks/CU x 256 CUs -- co-resident by construction

// ---- bf16 helpers (manual, RNE) ----
__device__ __forceinline__ unsigned short f2bf(float f) {
    union { float f; unsigned u; } v; v.f = f;
    unsigned r = v.u + 0x7FFF + ((v.u >> 16) & 1);
    return (unsigned short)(r >> 16);
}
__device__ __forceinline__ float bf2f(unsigned short h) {
    union { unsigned u; float f; } v; v.u = ((unsigned)h) << 16;
    return v.f;
}
__device__ __forceinline__ int rdlane(int v, int l) {
    return __builtin_amdgcn_readlane(v, l);
}

// software grid barrier (device/agent scope; all blocks co-resident)
__device__ __forceinline__ void gbar(int* ctr, int target) {
    __syncthreads();
    if (threadIdx.x == 0) {
        __hip_atomic_fetch_add(ctr, 1, __ATOMIC_ACQ_REL, __HIP_MEMORY_SCOPE_AGENT);
        while (__hip_atomic_load(ctr, __ATOMIC_ACQUIRE, __HIP_MEMORY_SCOPE_AGENT) < target)
            __builtin_amdgcn_s_sleep(2);
    }
    __syncthreads();
}

// ================= persistent CSR build (one kernel, 6 phases) =================
// ph1 hist -> ph2 tile-reduce -> ph3 {scan tsum | gstart | zero partial}
// -> ph4 scanC -> ph5 append -> ph6 bucket_csr
__global__ __launch_bounds__(256, 4) void build_k(
    const int* __restrict__ src, const int* __restrict__ dst,
    const int* __restrict__ batch,
    int* __restrict__ hist, int* __restrict__ tsum, int* __restrict__ scanned,
    int* __restrict__ pairs, int* __restrict__ offsets, float* __restrict__ dis,
    int* __restrict__ csr_src, int* __restrict__ gstart,
    float* __restrict__ partial, int psz, int* __restrict__ ctr,
    int N, int E, int G, int chunk, int ntiles, int nbuck)
{
    __shared__ int lds[1024];   // 4 KB, reused per phase (gbar separates uses)
    int t  = threadIdx.x;
    int b  = blockIdx.x;
    int nb = gridDim.x;

    // ---- ph1: per-chunk dst-bucket histogram ----
    if (b < NBLK) {
        for (int i = t; i < NBKT; i += 256) lds[i] = 0;
        __syncthreads();
        int base = b * chunk, end = min(base + chunk, E);
        for (int i = base + t; i < end; i += 256)
            atomicAdd(&lds[dst[i] >> 7], 1);
        __syncthreads();
        for (int i = t; i < NBKT; i += 256)
            hist[b * NBKT + i] = lds[i];
    }
    gbar(ctr, nb * 1);

    // ---- ph2: tile reduce in logical order l = bkt*NBLK + blk ----
    if (b < ntiles) {
        int l = b * 256 + t;
        int phys = (l & (NBLK - 1)) * NBKT + (l >> LOG_NBLK);
        lds[t] = hist[phys];
        __syncthreads();
        for (int off = 128; off > 0; off >>= 1) {
            if (t < off) lds[t] += lds[t + off];
            __syncthreads();
        }
        if (t == 0) tsum[b] = lds[0];
    }
    gbar(ctr, nb * 2);

    // ---- ph3: block0 scans tsum (ntiles<=512); block1 gstart; rest zero partial
    if (b == 0) {
        int a0 = (2 * t     < ntiles) ? tsum[2 * t]     : 0;
        int a1 = (2 * t + 1 < ntiles) ? tsum[2 * t + 1] : 0;
        int p = a0 + a1;
        lds[t] = p;
        __syncthreads();
        for (int off = 1; off < 256; off <<= 1) {
            int u = (t >= off) ? lds[t - off] : 0;
            __syncthreads();
            lds[t] += u;
            __syncthreads();
        }
        int exclp = lds[t] - p;
        if (2 * t     < ntiles) tsum[2 * t]     = exclp;
        if (2 * t + 1 < ntiles) tsum[2 * t + 1] = exclp + a0;
    } else if (b == 1) {
        if (t <= G) {
            if (t == G) gstart[t] = N;
            else {
                int lo = 0, hi = N;
                while (lo < hi) { int m = (lo + hi) >> 1; if (batch[m] < t) lo = m + 1; else hi = m; }
                gstart[t] = lo;
            }
        }
    } else {
        for (int i = (b - 2) * 256 + t; i < psz; i += (nb - 2) * 256) partial[i] = 0.f;
    }
    gbar(ctr, nb * 3);

    // ---- ph4: local scan + tile base -> scanned (logical layout) ----
    if (b < ntiles) {
        int l = b * 256 + t;
        int phys = (l & (NBLK - 1)) * NBKT + (l >> LOG_NBLK);
        int own = hist[phys];
        lds[t] = own;
        __syncthreads();
        for (int off = 1; off < 256; off <<= 1) {
            int u = (t >= off) ? lds[t - off] : 0;
            __syncthreads();
            lds[t] += u;
            __syncthreads();
        }
        scanned[l] = tsum[b] + lds[t] - own;
    }
    gbar(ctr, nb * 4);

    // ---- ph5: bucket-sorted append of packed (src<<7 | dst&127) ----
    if (b < NBLK) {
        for (int i = t; i < NBKT; i += 256) lds[i] = scanned[i * NBLK + b];
        __syncthreads();
        int base = b * chunk, end = min(base + chunk, E);
        for (int i = base + t; i < end; i += 256) {
            int s = src[i], d = dst[i];
            int pz = atomicAdd(&lds[d >> 7], 1);
            pairs[pz] = (s << 7) | (d & 127);
        }
    }
    gbar(ctr, nb * 5);

    // ---- ph6: per-bucket counts -> offsets/dis, then in-bucket scatter ----
    if (b < nbuck) {
        int* cnt = lds;          // 128
        int* sc  = lds + 128;    // 128
        int* cur = lds + 256;    // 128
        int nodeBase = b * 128;
        int nNodes = min(128, N - nodeBase);
        int bBase = scanned[b * NBLK];
        int bEnd  = (b + 1 < NBKT) ? scanned[(b + 1) * NBLK] : E;

        if (t < 128) cnt[t] = 0;
        __syncthreads();
        for (int i = bBase + t; i < bEnd; i += 256)
            atomicAdd(&cnt[pairs[i] & 127], 1);
        __syncthreads();
        int myc = (t < 128) ? cnt[t] : 0;
        if (t < 128) sc[t] = myc;
        __syncthreads();
        for (int off = 1; off < 128; off <<= 1) {
            int u = (t < 128 && t >= off) ? sc[t - off] : 0;
            __syncthreads();
            if (t < 128) sc[t] += u;
            __syncthreads();
        }
        if (t < 128) {
            int excl = sc[t] - myc;
            cur[t] = excl;
            if (t < nNodes) {
                offsets[nodeBase + t] = bBase + excl;
                dis[nodeBase + t] = rsqrtf(1.0f + (float)myc);
            }
        }
        if (t == 0 && b == nbuck - 1) offsets[N] = E;
        __syncthreads();
        for (int i = bBase + t; i < bEnd; i += 256) {
            int pk = pairs[i];
            int pos = bBase + atomicAdd(&cur[pk & 127], 1);
            csr_src[pos] = ((unsigned)pk) >> 7;
        }
    }
}

// ================= layers (r13-proven) =================

// register-tiled 64x64 GEMM, bf16 output PREMULTIPLIED by dis[row]:
// outb[r,c] = f2bf(dis[r] * (act(in+b_prev) @ W)[r,c]).  Row n of outb zeroed.
__global__ __launch_bounds__(256) void gemm64_k(
    const float* __restrict__ in, const float* __restrict__ b_prev, int relu_prev,
    const float* __restrict__ W, const float* __restrict__ dis,
    unsigned short* __restrict__ outb, int n)
{
    __shared__ float HsT[HD][68];
    __shared__ float Ws[HD][HD];
    int t = threadIdx.x;
    int rowBase = blockIdx.x * 64;

    for (int i = t; i < HD * HD / 4; i += 256)
        ((float4*)Ws)[i] = ((const float4*)W)[i];

    if (blockIdx.x == 0 && t < 64)   // zero pad-row n (gather target for tails)
        outb[(size_t)n * HD + t] = 0;

    {
        int k0 = (t & 15) * 4;
        float4 bb = make_float4(0.f, 0.f, 0.f, 0.f);
        if (b_prev) bb = *(const float4*)&b_prev[k0];
        for (int it = 0; it < 4; ++it) {
            int r = (t >> 4) + it * 16;
            int row = rowBase + r;
            float4 v = make_float4(0.f, 0.f, 0.f, 0.f);
            if (row < n) {
                v = *(const float4*)&in[(size_t)row * HD + k0];
                v.x += bb.x; v.y += bb.y; v.z += bb.z; v.w += bb.w;
                if (relu_prev) {
                    v.x = fmaxf(v.x, 0.f); v.y = fmaxf(v.y, 0.f);
                    v.z = fmaxf(v.z, 0.f); v.w = fmaxf(v.w, 0.f);
                }
            }
            HsT[k0 + 0][r] = v.x;
            HsT[k0 + 1][r] = v.y;
            HsT[k0 + 2][r] = v.z;
            HsT[k0 + 3][r] = v.w;
        }
    }
    __syncthreads();

    int c4 = (t & 15) * 4;
    int r4 = (t >> 4) * 4;
    float acc[4][4];
    #pragma unroll
    for (int i = 0; i < 4; ++i)
        #pragma unroll
        for (int j = 0; j < 4; ++j) acc[i][j] = 0.f;

    #pragma unroll 8
    for (int k = 0; k < HD; ++k) {
        float4 a = *(const float4*)&HsT[k][r4];
        float4 b = *(const float4*)&Ws[k][c4];
        acc[0][0] += a.x * b.x; acc[0][1] += a.x * b.y; acc[0][2] += a.x * b.z; acc[0][3] += a.x * b.w;
        acc[1][0] += a.y * b.x; acc[1][1] += a.y * b.y; acc[1][2] += a.y * b.z; acc[1][3] += a.y * b.w;
        acc[2][0] += a.z * b.x; acc[2][1] += a.z * b.y; acc[2][2] += a.z * b.z; acc[2][3] += a.z * b.w;
        acc[3][0] += a.w * b.x; acc[3][1] += a.w * b.y; acc[3][2] += a.w * b.z; acc[3][3] += a.w * b.w;
    }

    #pragma unroll
    for (int i = 0; i < 4; ++i) {
        int row = rowBase + r4 + i;
        if (row < n) {
            float ds = dis[row];
            ushort4 o;
            o.x = f2bf(ds * acc[i][0]); o.y = f2bf(ds * acc[i][1]);
            o.z = f2bf(ds * acc[i][2]); o.w = f2bf(ds * acc[i][3]);
            *(ushort4*)&outb[(size_t)row * HD + c4] = o;
        }
    }
}

// CSR gather-aggregate over dis-premultiplied bf16 table: pure adds.
// agg[n] = dis[n] * (h'[n] + sum h'[src]); tail lanes point at zero row n.
__global__ __launch_bounds__(256) void agg_csr_k(const unsigned short* __restrict__ hwb,
    const float* __restrict__ dis, const int* __restrict__ offsets,
    const int* __restrict__ csr_src, float* __restrict__ agg, int n)
{
    int wid  = (blockIdx.x * blockDim.x + threadIdx.x) >> 6;
    int lane = threadIdx.x & 63;
    if (wid >= n) return;
    float acc = bf2f(hwb[(size_t)wid * HD + lane]);   // self-loop (pre-dn)
    int beg = offsets[wid], end = offsets[wid + 1];

    for (int base = beg; base < end; base += 64) {
        int m = min(64, end - base);
        int idx = (lane < m) ? csr_src[base + lane] : n;   // pad -> zero row
        for (int j = 0; j < m; j += 16) {
            int ss[16];
            float h[16];
            #pragma unroll
            for (int u = 0; u < 16; ++u)
                ss[u] = rdlane(idx, j + u);                // j+u < 64 always
            #pragma unroll
            for (int u = 0; u < 16; ++u)
                h[u] = bf2f(hwb[(size_t)ss[u] * HD + lane]);  // 16 in flight
            #pragma unroll
            for (int u = 0; u < 16; ++u)
                acc += h[u];
        }
    }
    agg[(size_t)wid * HD + lane] = dis[wid] * acc;
}

// Layer-3 agg fused with pool stage 1 (atomic into partial[g][slot][64]).
__global__ __launch_bounds__(256) void agg_pool_k(const unsigned short* __restrict__ hwb,
    const float* __restrict__ dis, const int* __restrict__ offsets,
    const int* __restrict__ csr_src, const int* __restrict__ batch,
    float* __restrict__ partial, int n)
{
    __shared__ float rows[4 * HD];
    __shared__ int   gid[4];
    int t    = threadIdx.x;
    int lane = t & 63;
    int w    = t >> 6;
    int wid  = (blockIdx.x * blockDim.x + t) >> 6;

    rows[t] = 0.f;
    if (t < 4) gid[t] = -1;

    if (wid < n) {
        float acc = bf2f(hwb[(size_t)wid * HD + lane]);
        int beg = offsets[wid], end = offsets[wid + 1];
        for (int base = beg; base < end; base += 64) {
            int m = min(64, end - base);
            int idx = (lane < m) ? csr_src[base + lane] : n;
            for (int j = 0; j < m; j += 16) {
                int ss[16];
                float h[16];
                #pragma unroll
                for (int u = 0; u < 16; ++u)
                    ss[u] = rdlane(idx, j + u);
                #pragma unroll
                for (int u = 0; u < 16; ++u)
                    h[u] = bf2f(hwb[(size_t)ss[u] * HD + lane]);
                #pragma unroll
                for (int u = 0; u < 16; ++u)
                    acc += h[u];
            }
        }
        rows[w * HD + lane] = dis[wid] * acc;
        if (lane == 0) gid[w] = batch[wid];
    }
    __syncthreads();

    if (t < HD) {
        int g0 = gid[0], g1 = gid[1], g2 = gid[2], g3 = gid[3];
        int slot = blockIdx.x & (PSUB - 1);
        if (g0 == g1 && g1 == g2 && g2 == g3 && g0 >= 0) {
            float v = rows[t] + rows[HD + t] + rows[2 * HD + t] + rows[3 * HD + t];
            atomicAdd(&partial[((size_t)g0 * PSUB + slot) * HD + t], v);
        } else {
            if (g0 >= 0) atomicAdd(&partial[((size_t)g0 * PSUB + slot) * HD + t], rows[t]);
            if (g1 >= 0) atomicAdd(&partial[((size_t)g1 * PSUB + slot) * HD + t], rows[HD + t]);
            if (g2 >= 0) atomicAdd(&partial[((size_t)g2 * PSUB + slot) * HD + t], rows[2 * HD + t]);
            if (g3 >= 0) atomicAdd(&partial[((size_t)g3 * PSUB + slot) * HD + t], rows[3 * HD + t]);
        }
    }
}

// pooling stage 2: reduce partials, mean + b3, final linear
__global__ __launch_bounds__(64) void pool2_k(const float* __restrict__ partial,
    const int* __restrict__ gstart, const float* __restrict__ b3,
    const float* __restrict__ Wl, const float* __restrict__ bl,
    float* __restrict__ out, int O)
{
    __shared__ float pooled[HD];
    int g = blockIdx.x;
    int t = threadIdx.x;
    float sum = 0.0f;
    #pragma unroll
    for (int s = 0; s < PSUB; ++s)
        sum += partial[((size_t)g * PSUB + s) * HD + t];
    float cnt = (float)(gstart[g + 1] - gstart[g]);
    pooled[t] = sum / cnt + b3[t];
    __syncthreads();
    if (t < O) {
        float acc = bl[t];
        #pragma unroll
        for (int k = 0; k < HD; ++k) acc += pooled[k] * Wl[k * O + t];
        out[g * O + t] = acc;
    }
}

extern "C" void kernel_launch(void* const* d_in, const int* in_sizes, int n_in,
                              void* d_out, int out_size, void* d_ws, size_t ws_size,
                              hipStream_t stream)
{
    const float* x    = (const float*)d_in[0];
    const int*   ei   = (const int*)d_in[1];
    const int*   batch= (const int*)d_in[2];
    const float* W1   = (const float*)d_in[3];
    const float* b1   = (const float*)d_in[4];
    const float* W2   = (const float*)d_in[5];
    const float* b2   = (const float*)d_in[6];
    const float* W3   = (const float*)d_in[7];
    const float* b3   = (const float*)d_in[8];
    const float* Wl   = (const float*)d_in[9];
    const float* bl   = (const float*)d_in[10];
    float* out = (float*)d_out;

    const int N = in_sizes[0] / HD;
    const int E = in_sizes[1] / 2;
    const int O = in_sizes[10];
    const int G = out_size / O;

    const int* src = ei;
    const int* dst = ei + E;

    // ---- workspace layout (256 B aligned) ----
    char* p = (char*)d_ws;
    auto take = [&](size_t bytes) { char* r = p; p += (bytes + 255) & ~(size_t)255; return r; };
    int*   csr_src = (int*)  take((size_t)(E + 256) * 4);  // padded for over-read
    int*   offsets = (int*)  take((size_t)(N + 1) * 4);
    float* dis     = (float*)take((size_t)N * 4);
    int*   gstart  = (int*)  take((size_t)(G + 1) * 4);
    int*   ctr     = (int*)  take(256);
    float* partial = (float*)take((size_t)G * PSUB * HD * 4);   // 256 KB
    float* aggF    = (float*)take((size_t)N * HD * 4);          // 12.8 MB
    unsigned short* hwb = (unsigned short*)take((size_t)(N + 1) * HD * 2);  // 6.4 MB (+zero row)

    // aliases into regions not yet live during CSR build:
    int* hist    = (int*)aggF;                 // NBLK*NBKT*4 = 512 KB
    int* scanned = hist + NBLK * NBKT;         // 512 KB
    int* tsum    = scanned + NBLK * NBKT;      // 2 KB
    int* pairs   = (int*)hwb;                  // E*4 = 3.2 MB (packed)

    const int TB = 256;
    int chunk   = (E + NBLK - 1) / NBLK;
    int ntiles  = (NBLK * NBKT) / 256;         // 512
    int nb_gemm = (N + 63) / 64;
    int nb_agg  = (N * 64 + TB - 1) / TB;
    int nbuck   = (N + 127) / 128;
    int psz     = G * PSUB * HD;

    // ---- CSR build: one persistent kernel with software grid barriers ----
    hipMemsetAsync(ctr, 0, 4, stream);
    build_k<<<GRID_BUILD, TB, 0, stream>>>(src, dst, batch, hist, tsum, scanned,
        pairs, offsets, dis, csr_src, gstart, partial, psz, ctr,
        N, E, G, chunk, ntiles, nbuck);

    // ---- layer 1 ----
    gemm64_k<<<nb_gemm, TB, 0, stream>>>(x, nullptr, 0, W1, dis, hwb, N);
    agg_csr_k<<<nb_agg, TB, 0, stream>>>(hwb, dis, offsets, csr_src, aggF, N);

    // ---- layer 2 ----
    gemm64_k<<<nb_gemm, TB, 0, stream>>>(aggF, b1, 1, W2, dis, hwb, N);
    agg_csr_k<<<nb_agg, TB, 0, stream>>>(hwb, dis, offsets, csr_src, aggF, N);

    // ---- layer 3: gemm, then agg fused with pool stage 1 ----
    gemm64_k<<<nb_gemm, TB, 0, stream>>>(aggF, b2, 1, W3, dis, hwb, N);
    agg_pool_k<<<nb_agg, TB, 0, stream>>>(hwb, dis, offsets, csr_src, batch, partial, N);

    // ---- pool stage 2 + final linear ----
    pool2_k<<<G, 64, 0, stream>>>(partial, gstart, b3, Wl, bl, out, O);
}

// Round 16
// 227.834 us; speedup vs baseline: 3.3144x; 3.3144x over previous
//
#include <hip/hip_runtime.h>

#define HD 64      // hidden/feature dim (D == H == 64)
#define PSUB 16    // partial slots per graph (pool accumulation spread)
#define NBLK 256   // histogram blocks (edge slices)
#define LOG_NBLK 8
#define NBKT 512   // dst buckets (bucket = dst >> 7, 128 nodes each; N <= 65536)

// ---- bf16 helpers (manual, RNE) ----
__device__ __forceinline__ unsigned short f2bf(float f) {
    union { float f; unsigned u; } v; v.f = f;
    unsigned r = v.u + 0x7FFF + ((v.u >> 16) & 1);
    return (unsigned short)(r >> 16);
}
__device__ __forceinline__ float bf2f(unsigned short h) {
    union { unsigned u; float f; } v; v.u = ((unsigned)h) << 16;
    return v.f;
}
__device__ __forceinline__ int rdlane(int v, int l) {
    return __builtin_amdgcn_readlane(v, l);
}

// ================= atomic-free bucketed CSR build =================

__global__ __launch_bounds__(256) void hist1_k(const int* __restrict__ dst,
                                               int* __restrict__ hist, int E, int chunk)
{
    __shared__ int lh[NBKT];
    int t = threadIdx.x;
    for (int i = t; i < NBKT; i += 256) lh[i] = 0;
    __syncthreads();
    int base = blockIdx.x * chunk;
    int end  = min(base + chunk, E);
    for (int i = base + t; i < end; i += 256)
        atomicAdd(&lh[dst[i] >> 7], 1);
    __syncthreads();
    for (int i = t; i < NBKT; i += 256)
        hist[blockIdx.x * NBKT + i] = lh[i];
}

// 2a) tile-reduce logical order l = bkt*NBLK + blk  (phys = blk*NBKT + bkt)
__global__ __launch_bounds__(256) void scanA_k(const int* __restrict__ hist,
                                               int* __restrict__ tsum)
{
    __shared__ int s[256];
    int t = threadIdx.x;
    int l = blockIdx.x * 256 + t;
    int phys = (l & (NBLK - 1)) * NBKT + (l >> LOG_NBLK);
    s[t] = hist[phys];
    __syncthreads();
    for (int off = 128; off > 0; off >>= 1) {
        if (t < off) s[t] += s[t + off];
        __syncthreads();
    }
    if (t == 0) tsum[blockIdx.x] = s[0];
}

// 2b) single block: exclusive-scan tsum; compute gstart; zero partial
__global__ __launch_bounds__(1024) void scanB_k(int* __restrict__ tsum, int nb,
    const int* __restrict__ batch, int* __restrict__ gstart, int n, int G,
    float* __restrict__ partial, int psz)
{
    __shared__ int s[1024];
    int t = threadIdx.x;
    int v = (t < nb) ? tsum[t] : 0;
    s[t] = v;
    __syncthreads();
    for (int off = 1; off < 1024; off <<= 1) {
        int u = (t >= off) ? s[t - off] : 0;
        __syncthreads();
        s[t] += u;
        __syncthreads();
    }
    if (t < nb) tsum[t] = s[t] - v;
    if (t <= G) {
        if (t == G) gstart[t] = n;
        else {
            int lo = 0, hi = n;
            while (lo < hi) { int m = (lo + hi) >> 1; if (batch[m] < t) lo = m + 1; else hi = m; }
            gstart[t] = lo;
        }
    }
    for (int i = t; i < psz; i += 1024) partial[i] = 0.f;
}

__global__ __launch_bounds__(256) void scanC_k(const int* __restrict__ hist,
                                               const int* __restrict__ tsum,
                                               int* __restrict__ scanned)
{
    __shared__ int s[256];
    int t = threadIdx.x;
    int l = blockIdx.x * 256 + t;
    int phys = (l & (NBLK - 1)) * NBKT + (l >> LOG_NBLK);
    int own = hist[phys];
    s[t] = own;
    __syncthreads();
    for (int off = 1; off < 256; off <<= 1) {
        int u = (t >= off) ? s[t - off] : 0;
        __syncthreads();
        s[t] += u;
        __syncthreads();
    }
    scanned[l] = tsum[blockIdx.x] + s[t] - own;
}

// 3) bucket-sorted append of packed (src<<7 | dst&127); per-block private ranges
__global__ __launch_bounds__(256) void append_k(const int* __restrict__ src,
    const int* __restrict__ dst, const int* __restrict__ scanned,
    int* __restrict__ pairs, int E, int chunk)
{
    __shared__ int cur[NBKT];
    int t = threadIdx.x;
    int blk = blockIdx.x;
    for (int i = t; i < NBKT; i += 256) cur[i] = scanned[i * NBLK + blk];
    __syncthreads();
    int base = blk * chunk;
    int end  = min(base + chunk, E);
    for (int i = base + t; i < end; i += 256) {
        int s = src[i], d = dst[i];
        int p = atomicAdd(&cur[d >> 7], 1);
        pairs[p] = (s << 7) | (d & 127);
    }
}

// 4) per-bucket: node counts -> offsets/dis, then in-bucket scatter of csr_src
__global__ __launch_bounds__(256) void bucket_csr_k(const int* __restrict__ pairs,
    const int* __restrict__ scanned, int* __restrict__ offsets,
    float* __restrict__ dis, int* __restrict__ csr_src, int N, int E)
{
    __shared__ int cnt[128];
    __shared__ int sc[128];
    __shared__ int cur[128];
    int t = threadIdx.x;
    int b = blockIdx.x;
    int nodeBase = b * 128;
    int nNodes = min(128, N - nodeBase);
    int bBase = scanned[b * NBLK];
    int bEnd  = (b + 1 < NBKT) ? scanned[(b + 1) * NBLK] : E;

    if (t < 128) cnt[t] = 0;
    __syncthreads();
    for (int i = bBase + t; i < bEnd; i += 256)
        atomicAdd(&cnt[pairs[i] & 127], 1);
    __syncthreads();
    int myc = (t < 128) ? cnt[t] : 0;
    if (t < 128) sc[t] = myc;
    __syncthreads();
    for (int off = 1; off < 128; off <<= 1) {
        int u = (t < 128 && t >= off) ? sc[t - off] : 0;
        __syncthreads();
        if (t < 128) sc[t] += u;
        __syncthreads();
    }
    if (t < 128) {
        int excl = sc[t] - myc;
        cur[t] = excl;
        if (t < nNodes) {
            offsets[nodeBase + t] = bBase + excl;
            dis[nodeBase + t] = rsqrtf(1.0f + (float)myc);
        }
    }
    if (t == 0 && b == gridDim.x - 1) offsets[N] = E;
    __syncthreads();
    for (int i = bBase + t; i < bEnd; i += 256) {
        int pk = pairs[i];
        int pos = bBase + atomicAdd(&cur[pk & 127], 1);
        csr_src[pos] = ((unsigned)pk) >> 7;
    }
}

// ================= layers =================

// register-tiled 64x64 GEMM, bf16 output PREMULTIPLIED by dis[row]:
// outb[r,c] = f2bf(dis[r] * (act(in+b_prev) @ W)[r,c]).  Row n of outb zeroed.
__global__ __launch_bounds__(256) void gemm64_k(
    const float* __restrict__ in, const float* __restrict__ b_prev, int relu_prev,
    const float* __restrict__ W, const float* __restrict__ dis,
    unsigned short* __restrict__ outb, int n)
{
    __shared__ float HsT[HD][68];
    __shared__ float Ws[HD][HD];
    int t = threadIdx.x;
    int rowBase = blockIdx.x * 64;

    for (int i = t; i < HD * HD / 4; i += 256)
        ((float4*)Ws)[i] = ((const float4*)W)[i];

    if (blockIdx.x == 0 && t < 64)   // zero pad-row n (gather target for tails)
        outb[(size_t)n * HD + t] = 0;

    {
        int k0 = (t & 15) * 4;
        float4 bb = make_float4(0.f, 0.f, 0.f, 0.f);
        if (b_prev) bb = *(const float4*)&b_prev[k0];
        for (int it = 0; it < 4; ++it) {
            int r = (t >> 4) + it * 16;
            int row = rowBase + r;
            float4 v = make_float4(0.f, 0.f, 0.f, 0.f);
            if (row < n) {
                v = *(const float4*)&in[(size_t)row * HD + k0];
                v.x += bb.x; v.y += bb.y; v.z += bb.z; v.w += bb.w;
                if (relu_prev) {
                    v.x = fmaxf(v.x, 0.f); v.y = fmaxf(v.y, 0.f);
                    v.z = fmaxf(v.z, 0.f); v.w = fmaxf(v.w, 0.f);
                }
            }
            HsT[k0 + 0][r] = v.x;
            HsT[k0 + 1][r] = v.y;
            HsT[k0 + 2][r] = v.z;
            HsT[k0 + 3][r] = v.w;
        }
    }
    __syncthreads();

    int c4 = (t & 15) * 4;
    int r4 = (t >> 4) * 4;
    float acc[4][4];
    #pragma unroll
    for (int i = 0; i < 4; ++i)
        #pragma unroll
        for (int j = 0; j < 4; ++j) acc[i][j] = 0.f;

    #pragma unroll 8
    for (int k = 0; k < HD; ++k) {
        float4 a = *(const float4*)&HsT[k][r4];
        float4 b = *(const float4*)&Ws[k][c4];
        acc[0][0] += a.x * b.x; acc[0][1] += a.x * b.y; acc[0][2] += a.x * b.z; acc[0][3] += a.x * b.w;
        acc[1][0] += a.y * b.x; acc[1][1] += a.y * b.y; acc[1][2] += a.y * b.z; acc[1][3] += a.y * b.w;
        acc[2][0] += a.z * b.x; acc[2][1] += a.z * b.y; acc[2][2] += a.z * b.z; acc[2][3] += a.z * b.w;
        acc[3][0] += a.w * b.x; acc[3][1] += a.w * b.y; acc[3][2] += a.w * b.z; acc[3][3] += a.w * b.w;
    }

    #pragma unroll
    for (int i = 0; i < 4; ++i) {
        int row = rowBase + r4 + i;
        if (row < n) {
            float ds = dis[row];
            ushort4 o;
            o.x = f2bf(ds * acc[i][0]); o.y = f2bf(ds * acc[i][1]);
            o.z = f2bf(ds * acc[i][2]); o.w = f2bf(ds * acc[i][3]);
            *(ushort4*)&outb[(size_t)row * HD + c4] = o;
        }
    }
}

// CSR gather-aggregate over dis-premultiplied bf16 table: pure adds.
// agg[n] = dis[n] * (h'[n] + sum h'[src]); tail lanes point at zero row n.
__global__ __launch_bounds__(256) void agg_csr_k(const unsigned short* __restrict__ hwb,
    const float* __restrict__ dis, const int* __restrict__ offsets,
    const int* __restrict__ csr_src, float* __restrict__ agg, int n)
{
    int wid  = (blockIdx.x * blockDim.x + threadIdx.x) >> 6;
    int lane = threadIdx.x & 63;
    if (wid >= n) return;
    float acc = bf2f(hwb[(size_t)wid * HD + lane]);   // self-loop (pre-dn)
    int beg = offsets[wid], end = offsets[wid + 1];

    for (int base = beg; base < end; base += 64) {
        int m = min(64, end - base);
        int idx = (lane < m) ? csr_src[base + lane] : n;   // pad -> zero row
        for (int j = 0; j < m; j += 16) {
            int ss[16];
            float h[16];
            #pragma unroll
            for (int u = 0; u < 16; ++u)
                ss[u] = rdlane(idx, j + u);                // j+u < 64 always
            #pragma unroll
            for (int u = 0; u < 16; ++u)
                h[u] = bf2f(hwb[(size_t)ss[u] * HD + lane]);  // 16 in flight
            #pragma unroll
            for (int u = 0; u < 16; ++u)
                acc += h[u];
        }
    }
    agg[(size_t)wid * HD + lane] = dis[wid] * acc;
}

// Layer-3 agg fused with pool stage 1 (atomic into partial[g][slot][64]).
__global__ __launch_bounds__(256) void agg_pool_k(const unsigned short* __restrict__ hwb,
    const float* __restrict__ dis, const int* __restrict__ offsets,
    const int* __restrict__ csr_src, const int* __restrict__ batch,
    float* __restrict__ partial, int n)
{
    __shared__ float rows[4 * HD];
    __shared__ int   gid[4];
    int t    = threadIdx.x;
    int lane = t & 63;
    int w    = t >> 6;
    int wid  = (blockIdx.x * blockDim.x + t) >> 6;

    rows[t] = 0.f;
    if (t < 4) gid[t] = -1;

    if (wid < n) {
        float acc = bf2f(hwb[(size_t)wid * HD + lane]);
        int beg = offsets[wid], end = offsets[wid + 1];
        for (int base = beg; base < end; base += 64) {
            int m = min(64, end - base);
            int idx = (lane < m) ? csr_src[base + lane] : n;
            for (int j = 0; j < m; j += 16) {
                int ss[16];
                float h[16];
                #pragma unroll
                for (int u = 0; u < 16; ++u)
                    ss[u] = rdlane(idx, j + u);
                #pragma unroll
                for (int u = 0; u < 16; ++u)
                    h[u] = bf2f(hwb[(size_t)ss[u] * HD + lane]);
                #pragma unroll
                for (int u = 0; u < 16; ++u)
                    acc += h[u];
            }
        }
        rows[w * HD + lane] = dis[wid] * acc;
        if (lane == 0) gid[w] = batch[wid];
    }
    __syncthreads();

    if (t < HD) {
        int g0 = gid[0], g1 = gid[1], g2 = gid[2], g3 = gid[3];
        int slot = blockIdx.x & (PSUB - 1);
        if (g0 == g1 && g1 == g2 && g2 == g3 && g0 >= 0) {
            float v = rows[t] + rows[HD + t] + rows[2 * HD + t] + rows[3 * HD + t];
            atomicAdd(&partial[((size_t)g0 * PSUB + slot) * HD + t], v);
        } else {
            if (g0 >= 0) atomicAdd(&partial[((size_t)g0 * PSUB + slot) * HD + t], rows[t]);
            if (g1 >= 0) atomicAdd(&partial[((size_t)g1 * PSUB + slot) * HD + t], rows[HD + t]);
            if (g2 >= 0) atomicAdd(&partial[((size_t)g2 * PSUB + slot) * HD + t], rows[2 * HD + t]);
            if (g3 >= 0) atomicAdd(&partial[((size_t)g3 * PSUB + slot) * HD + t], rows[3 * HD + t]);
        }
    }
}

// pooling stage 2: reduce partials, mean + b3, final linear
__global__ __launch_bounds__(64) void pool2_k(const float* __restrict__ partial,
    const int* __restrict__ gstart, const float* __restrict__ b3,
    const float* __restrict__ Wl, const float* __restrict__ bl,
    float* __restrict__ out, int O)
{
    __shared__ float pooled[HD];
    int g = blockIdx.x;
    int t = threadIdx.x;
    float sum = 0.0f;
    #pragma unroll
    for (int s = 0; s < PSUB; ++s)
        sum += partial[((size_t)g * PSUB + s) * HD + t];
    float cnt = (float)(gstart[g + 1] - gstart[g]);
    pooled[t] = sum / cnt + b3[t];
    __syncthreads();
    if (t < O) {
        float acc = bl[t];
        #pragma unroll
        for (int k = 0; k < HD; ++k) acc += pooled[k] * Wl[k * O + t];
        out[g * O + t] = acc;
    }
}

extern "C" void kernel_launch(void* const* d_in, const int* in_sizes, int n_in,
                              void* d_out, int out_size, void* d_ws, size_t ws_size,
                              hipStream_t stream)
{
    const float* x    = (const float*)d_in[0];
    const int*   ei   = (const int*)d_in[1];
    const int*   batch= (const int*)d_in[2];
    const float* W1   = (const float*)d_in[3];
    const float* b1   = (const float*)d_in[4];
    const float* W2   = (const float*)d_in[5];
    const float* b2   = (const float*)d_in[6];
    const float* W3   = (const float*)d_in[7];
    const float* b3   = (const float*)d_in[8];
    const float* Wl   = (const float*)d_in[9];
    const float* bl   = (const float*)d_in[10];
    float* out = (float*)d_out;

    const int N = in_sizes[0] / HD;
    const int E = in_sizes[1] / 2;
    const int O = in_sizes[10];
    const int G = out_size / O;

    const int* src = ei;
    const int* dst = ei + E;

    // ---- workspace layout (256 B aligned) ----
    char* p = (char*)d_ws;
    auto take = [&](size_t bytes) { char* r = p; p += (bytes + 255) & ~(size_t)255; return r; };
    int*   csr_src = (int*)  take((size_t)(E + 256) * 4);  // padded for over-read
    int*   offsets = (int*)  take((size_t)(N + 1) * 4);
    float* dis     = (float*)take((size_t)N * 4);
    int*   gstart  = (int*)  take((size_t)(G + 1) * 4);
    float* partial = (float*)take((size_t)G * PSUB * HD * 4);   // 256 KB
    float* aggF    = (float*)take((size_t)N * HD * 4);          // 12.8 MB
    unsigned short* hwb = (unsigned short*)take((size_t)(N + 1) * HD * 2);  // 6.4 MB (+zero row)

    // aliases into regions not yet live during CSR build:
    int* hist    = (int*)aggF;                 // NBLK*NBKT*4 = 512 KB
    int* scanned = hist + NBLK * NBKT;         // 512 KB
    int* tsum    = scanned + NBLK * NBKT;      // 2 KB
    int* pairs   = (int*)hwb;                  // E*4 = 3.2 MB (packed)

    const int TB = 256;
    int chunk   = (E + NBLK - 1) / NBLK;
    int ntiles  = (NBLK * NBKT) / 256;         // 512
    int nb_gemm = (N + 63) / 64;
    int nb_agg  = (N * 64 + TB - 1) / TB;
    int nbuck   = (N + 127) / 128;
    int psz     = G * PSUB * HD;

    // ---- CSR build (atomic-free counting sort, packed pairs) ----
    hist1_k<<<NBLK, TB, 0, stream>>>(dst, hist, E, chunk);
    scanA_k<<<ntiles, TB, 0, stream>>>(hist, tsum);
    scanB_k<<<1, 1024, 0, stream>>>(tsum, ntiles, batch, gstart, N, G, partial, psz);
    scanC_k<<<ntiles, TB, 0, stream>>>(hist, tsum, scanned);
    append_k<<<NBLK, TB, 0, stream>>>(src, dst, scanned, pairs, E, chunk);
    bucket_csr_k<<<nbuck, TB, 0, stream>>>(pairs, scanned, offsets, dis, csr_src, N, E);

    // ---- layer 1 ----
    gemm64_k<<<nb_gemm, TB, 0, stream>>>(x, nullptr, 0, W1, dis, hwb, N);
    agg_csr_k<<<nb_agg, TB, 0, stream>>>(hwb, dis, offsets, csr_src, aggF, N);

    // ---- layer 2 ----
    gemm64_k<<<nb_gemm, TB, 0, stream>>>(aggF, b1, 1, W2, dis, hwb, N);
    agg_csr_k<<<nb_agg, TB, 0, stream>>>(hwb, dis, offsets, csr_src, aggF, N);

    // ---- layer 3: gemm, then agg fused with pool stage 1 ----
    gemm64_k<<<nb_gemm, TB, 0, stream>>>(aggF, b2, 1, W3, dis, hwb, N);
    agg_pool_k<<<nb_agg, TB, 0, stream>>>(hwb, dis, offsets, csr_src, batch, partial, N);

    // ---- pool stage 2 + final linear ----
    pool2_k<<<G, 64, 0, stream>>>(partial, gstart, b3, Wl, bl, out, O);
}